// Round 10
// baseline (137.481 us; speedup 1.0000x reference)
//
#include <hip/hip_runtime.h>
#include <math.h>

// Problem constants (reference: B=4, T=4096, D_MODEL=128, N_HEADS=4, HEAD_DIM=32)
#define B_   4
#define T_   4096
#define DM_  128
#define NH_  4
#define HD_  32
#define TOKENS (B_ * T_)               // 16384

typedef __attribute__((ext_vector_type(8))) short short8;   // 8 bf16 = 4 VGPRs (MFMA A/B frag)
typedef __attribute__((ext_vector_type(4))) float floatx4;  // MFMA C/D frag

__device__ __forceinline__ unsigned short f2bf(float f) {
    union { float f; unsigned int u; } v; v.f = f;
    unsigned int u = v.u;
    u += 0x7fffu + ((u >> 16) & 1u);   // round-to-nearest-even
    return (unsigned short)(u >> 16);
}
__device__ __forceinline__ void split_bf(float v, unsigned short& hi, unsigned short& lo) {
    unsigned short h = f2bf(v);
    float hf = __uint_as_float(((unsigned int)h) << 16);
    hi = h;
    lo = f2bf(v - hf);
}

// LDS row stride for bf16 W tiles: 128 elements + 8 pad = 136 shorts = 272 B.
#define LROW 136

// -------------------------------------------------------------------------
// Kernel 1: QKV projection via MFMA, hi/lo bf16 split, coalesced epilogue.
// (round-6/9 version, unchanged)
// -------------------------------------------------------------------------
__global__ __launch_bounds__(256) void qkv_proj_kernel(
    const float* __restrict__ x, const float* __restrict__ Wqkv,
    unsigned short* __restrict__ q_bf, unsigned short* __restrict__ k_bf,
    unsigned short* __restrict__ v_t)
{
    __shared__ __align__(16) unsigned short whi[64 * LROW];   // 17 KB
    __shared__ __align__(16) unsigned short wlo[64 * LROW];   // 17 KB

    const int tid  = threadIdx.x;
    const int wave = tid >> 6, lane = tid & 63;
    const int m    = lane & 15, q4 = lane >> 4;
    const int m0   = blockIdx.x * 64;
    const int ch   = blockIdx.y;                  // 0..5
    const float scale = 0.2550052509571414f;      // log2(e)/sqrt(32)

    {   // cooperative W chunk split: rows ch*64 .. +63
        const float4* wg = (const float4*)(Wqkv + (size_t)ch * 64 * DM_);
        #pragma unroll
        for (int i = 0; i < 8; ++i) {
            const int f = tid + 256 * i;
            float4 v = wg[f];
            const int row = f >> 5, k4 = f & 31;
            ushort4 h, l;
            split_bf(v.x, h.x, l.x); split_bf(v.y, h.y, l.y);
            split_bf(v.z, h.z, l.z); split_bf(v.w, h.w, l.w);
            *(ushort4*)(whi + row * LROW + k4 * 4) = h;
            *(ushort4*)(wlo + row * LROW + k4 * 4) = l;
        }
    }

    // A-frags direct from global: row m0+wave*16+m, cols ks*32+q4*8..+7
    short8 Ah[4], Al[4];
    {
        const float4* xg = (const float4*)(x + (size_t)(m0 + wave * 16 + m) * DM_);
        #pragma unroll
        for (int ks = 0; ks < 4; ++ks) {
            float4 a = xg[ks * 8 + q4 * 2];
            float4 b = xg[ks * 8 + q4 * 2 + 1];
            ushort4 h0, l0, h1, l1;
            split_bf(a.x, h0.x, l0.x); split_bf(a.y, h0.y, l0.y);
            split_bf(a.z, h0.z, l0.z); split_bf(a.w, h0.w, l0.w);
            split_bf(b.x, h1.x, l1.x); split_bf(b.y, h1.y, l1.y);
            split_bf(b.z, h1.z, l1.z); split_bf(b.w, h1.w, l1.w);
            Ah[ks] = short8{(short)h0.x, (short)h0.y, (short)h0.z, (short)h0.w,
                            (short)h1.x, (short)h1.y, (short)h1.z, (short)h1.w};
            Al[ks] = short8{(short)l0.x, (short)l0.y, (short)l0.z, (short)l0.w,
                            (short)l1.x, (short)l1.y, (short)l1.z, (short)l1.w};
        }
    }
    __syncthreads();

    floatx4 acc[4];
    #pragma unroll
    for (int nb = 0; nb < 4; ++nb) {
        floatx4 a = {0.f, 0.f, 0.f, 0.f};
        #pragma unroll
        for (int ks = 0; ks < 4; ++ks) {
            short8 Bh = *(const short8*)(whi + (nb * 16 + m) * LROW + ks * 32 + q4 * 8);
            short8 Bl = *(const short8*)(wlo + (nb * 16 + m) * LROW + ks * 32 + q4 * 8);
            a = __builtin_amdgcn_mfma_f32_16x16x32_bf16(Ah[ks], Bh, a, 0, 0, 0);
            a = __builtin_amdgcn_mfma_f32_16x16x32_bf16(Ah[ks], Bl, a, 0, 0, 0);
            a = __builtin_amdgcn_mfma_f32_16x16x32_bf16(Al[ks], Bh, a, 0, 0, 0);
        }
        acc[nb] = a;
    }
    __syncthreads();   // all waves done reading whi/wlo -> reuse whi as staging

    // stage C tile as bf16: [64 t][72] for q/k (t-major), [64 n][72] for v (n-major)
    unsigned short* stage = whi;
    const bool isV = (ch >= 4);
    if (isV) {
        #pragma unroll
        for (int nb = 0; nb < 4; ++nb) {
            ushort4 p;
            p.x = f2bf(acc[nb][0]); p.y = f2bf(acc[nb][1]);
            p.z = f2bf(acc[nb][2]); p.w = f2bf(acc[nb][3]);
            *(ushort4*)(stage + (nb * 16 + m) * 72 + wave * 16 + q4 * 4) = p;
        }
    } else {
        const float scl = (ch < 2) ? scale : 1.0f;
        #pragma unroll
        for (int nb = 0; nb < 4; ++nb)
            #pragma unroll
            for (int reg = 0; reg < 4; ++reg)
                stage[(wave * 16 + q4 * 4 + reg) * 72 + nb * 16 + m]
                    = f2bf(acc[nb][reg] * scl);
    }
    __syncthreads();

    // coalesced write-out: 32B (2 x short8) per thread
    const int b    = m0 >> 12;
    const int t0   = m0 & (T_ - 1);
    const int head = tid >> 7;                 // 0..1 (n_local 0..31 / 32..63)
    const int hh   = (ch * 2 + head) & 3;
    const int bh   = b * NH_ + hh;
    const int r    = tid & 127;
    if (isV) {
        const int d = r >> 2, qc = r & 3;      // 32 d-rows x 4 t-chunks of 16
        const unsigned short* sp = stage + (head * 32 + d) * 72 + qc * 16;
        short8 v0 = *(const short8*)(sp);
        short8 v1 = *(const short8*)(sp + 8);
        unsigned short* gp = v_t + ((size_t)bh * HD_ + d) * T_ + t0 + qc * 16;
        *(short8*)(gp)     = v0;
        *(short8*)(gp + 8) = v1;
    } else {
        unsigned short* dst = (ch < 2) ? q_bf : k_bf;
        const int t = r >> 1, half = r & 1;    // 64 t-rows x 2 x 32B halves
        const unsigned short* sp = stage + t * 72 + head * 32 + half * 16;
        short8 v0 = *(const short8*)(sp);
        short8 v1 = *(const short8*)(sp + 8);
        unsigned short* gp = dst + ((size_t)bh * T_ + t0 + t) * HD_ + half * 16;
        *(short8*)(gp)     = v0;
        *(short8*)(gp + 8) = v1;
    }
}

// -------------------------------------------------------------------------
// Kernel 2: bf16 MFMA causal flash attention + FUSED OUTPUT PROJECTION.
// Online loop = EXACT round-9 passing code (perm pack, ones-MFMA psum,
// async-STAGE).  New epilogue: normalized O staged to LDS (reusing kLds,
// padded rows); Wout head-slice hi/lo-split to LDS (reusing vLds + pT);
// 24 MFMA/wave (same 3-MFMA hi/lo scheme as the old out_proj kernel) and
// fp32 atomicAdd into the final output (4 heads accumulate per element).
// out_proj kernel and the 24MB att_ws round-trip are eliminated.
// -------------------------------------------------------------------------
template<bool LAST>
__device__ __forceinline__ void attn_tile128(
    const char* kLds, const char* vLds, char* pT,
    const int m, const int q4, const short8 qf, const short8 ones,
    const int sbN_in, const int limit,
    floatx4& O0, floatx4& O1, float& mx, float& ls)
{
    const int sbN = LAST ? sbN_in : 8;        // active 16-key sub-frags
    const int kN  = sbN >> 1;                 // active 32-key PV slots

    // S^T = K·Q^T : A = K rows (s), B = Q rows (q).  C[s=q4*4+reg][q=m]
    floatx4 st[8];
    #pragma unroll
    for (int sb = 0; sb < 8; ++sb) {
        if (sb >= sbN) continue;
        short8 kfrag = *(const short8*)(kLds + (sb * 16 + m) * 80 + q4 * 16);
        floatx4 z = {0.f, 0.f, 0.f, 0.f};
        st[sb] = __builtin_amdgcn_mfma_f32_16x16x32_bf16(kfrag, qf, z, 0, 0, 0);
    }

    if (LAST) {   // causal: mask s_local > limit
        #pragma unroll
        for (int sb = 0; sb < 8; ++sb) {
            if (sb >= sbN) continue;
            #pragma unroll
            for (int reg = 0; reg < 4; ++reg)
                if (sb * 16 + q4 * 4 + reg > limit) st[sb][reg] = -INFINITY;
        }
    }

    // per-lane row max over 32 s-values (tree) + 2 cross-quad shuffles
    float fm[8];
    #pragma unroll
    for (int sb = 0; sb < 8; ++sb)
        fm[sb] = (sb < sbN) ? fmaxf(fmaxf(st[sb][0], st[sb][1]),
                                    fmaxf(st[sb][2], st[sb][3]))
                            : -INFINITY;
    float rmax = fmaxf(fmaxf(fmaxf(fm[0], fm[1]), fmaxf(fm[2], fm[3])),
                       fmaxf(fmaxf(fm[4], fm[5]), fmaxf(fm[6], fm[7])));
    rmax = fmaxf(rmax, __shfl_xor(rmax, 16, 64));
    rmax = fmaxf(rmax, __shfl_xor(rmax, 32, 64));

    const float mn = fmaxf(mx, rmax);
    const float alpha = __builtin_amdgcn_exp2f(mx - mn);   // exp2(-inf)=0 first step
    mx = mn;

    // p = exp2(s - mn); pack hi16 (round-half-up) via v_perm; b64 writes
    // swizzled 16B granule: g = (2*sb + (q4>>1)) ^ m, half = q4&1
    #pragma unroll
    for (int sb = 0; sb < 8; ++sb) {
        if (sb >= sbN) continue;
        float p0 = __builtin_amdgcn_exp2f(st[sb][0] - mn);
        float p1 = __builtin_amdgcn_exp2f(st[sb][1] - mn);
        float p2 = __builtin_amdgcn_exp2f(st[sb][2] - mn);
        float p3 = __builtin_amdgcn_exp2f(st[sb][3] - mn);
        unsigned u0 = __float_as_uint(p0) + 0x8000u;
        unsigned u1 = __float_as_uint(p1) + 0x8000u;
        unsigned u2 = __float_as_uint(p2) + 0x8000u;
        unsigned u3 = __float_as_uint(p3) + 0x8000u;
        uint2 pk;
        pk.x = __builtin_amdgcn_perm(u1, u0, 0x07060302);  // [bf(p0) | bf(p1)<<16]
        pk.y = __builtin_amdgcn_perm(u3, u2, 0x07060302);
        *(uint2*)(pT + ((((2 * sb + (q4 >> 1)) ^ m) << 4) + (q4 & 1) * 8)) = pk;
    }
    #pragma unroll
    for (int reg = 0; reg < 4; ++reg) { O0[reg] *= alpha; O1[reg] *= alpha; }

    // drain wave-internal P^T writes before cross-lane B-frag reads
    __asm__ volatile("s_waitcnt lgkmcnt(0)" ::: "memory");
    __builtin_amdgcn_sched_barrier(0);   // rule #18: keep MFMA below the fence

    // O^T += V^T · P^T ; row-sum of P via ones-MFMA (C row = col-sum of B):
    // ps[reg] = sum_k P^T[k][q=m], identical across regs -> no shuffles.
    floatx4 ps = {0.f, 0.f, 0.f, 0.f};
    #pragma unroll
    for (int ks = 0; ks < 4; ++ks) {
        if (ks >= kN) continue;
        short8 bfrag = *(const short8*)(pT + (((ks * 4 + q4) ^ m) << 4));
        short8 va = *(const short8*)(vLds + m * 272 + ks * 64 + q4 * 16);
        short8 vb = *(const short8*)(vLds + (16 + m) * 272 + ks * 64 + q4 * 16);
        O0 = __builtin_amdgcn_mfma_f32_16x16x32_bf16(va, bfrag, O0, 0, 0, 0);
        O1 = __builtin_amdgcn_mfma_f32_16x16x32_bf16(vb, bfrag, O1, 0, 0, 0);
        ps = __builtin_amdgcn_mfma_f32_16x16x32_bf16(ones, bfrag, ps, 0, 0, 0);
    }
    ls = ls * alpha + ps[0];
}

__global__ __launch_bounds__(256, 4) void attn_mfma_kernel(
    const unsigned short* __restrict__ qb, const unsigned short* __restrict__ kb,
    const unsigned short* __restrict__ vtb, const float* __restrict__ Wout,
    float* __restrict__ out)
{
    // LDS: K 128x80B | V^T 32x272B | P^T 4 waves x 16 rows x 256B
    __shared__ __align__(16) char smem[10240 + 8704 + 4 * 4096];   // 35328 B
    char* kLds = smem;
    char* vLds = smem + 10240;
    const int tid  = threadIdx.x;
    const int wave = tid >> 6, lane = tid & 63;
    const int m    = lane & 15, q4 = lane >> 4;
    char* pT = smem + 18944 + wave * 4096 + m * 256;   // this lane's P^T row base

    // Dispatch swizzle: XCD-locality (2 heads per XCD) + per-CU qt balance.
    const int pid = blockIdx.x;
    const int xcd = pid & 7;
    const int r_  = pid >> 3;
    const int bh  = xcd * 2 + (r_ & 1);
    const int j_  = r_ >> 1;
    const int a_  = j_ & 15, k_ = j_ >> 4;
    const int qt  = (k_ == 0) ? a_ : (k_ == 1) ? 63 - a_
                  : (k_ == 2) ? 32 + a_ : 31 - a_;

    const size_t qkbase = (size_t)bh * T_ * HD_;
    const char* kg = (const char*)(kb + qkbase);
    const char* vg = (const char*)(vtb + qkbase);

    // Q B-fragment: row qt*64+wave*16+m, k-bytes q4*16 (Q pre-scaled, exp2 domain)
    short8 qf = *(const short8*)((const char*)(qb + qkbase)
                 + (size_t)(qt * 64 + wave * 16 + m) * 64 + q4 * 16);
    const int qrow = wave * 16 + m;        // query row within the 64-block

    const short8 ones = short8{(short)0x3F80, (short)0x3F80, (short)0x3F80,
                               (short)0x3F80, (short)0x3F80, (short)0x3F80,
                               (short)0x3F80, (short)0x3F80};   // bf16 1.0 x8

    floatx4 O0 = {0.f, 0.f, 0.f, 0.f}, O1 = {0.f, 0.f, 0.f, 0.f};
    float mx = -INFINITY, ls = 0.f;

    const int itN      = (qt >> 1) + 1;            // 128-key steps
    const int sbN_last = (qt & 1) ? 8 : 4;         // active sub-frags on diagonal
    const int limit    = ((qt & 1) << 6) + qrow;   // causal mask threshold

    // async-STAGE: per-thread staging addresses + prologue load of step 0
    const int krow = tid >> 2, ku = tid & 3;
    const int vd = tid >> 3, vu = tid & 7;
    const char* kstage = kg + (size_t)krow * 64 + ku * 16;
    const char* vstage = vg + (size_t)vd * (T_ * 2) + vu * 16;

    short8 sk0 = *(const short8*)(kstage);
    short8 sk1 = *(const short8*)(kstage + 64 * 64);
    short8 sv0 = *(const short8*)(vstage);
    short8 sv1 = *(const short8*)(vstage + 128);

    for (int it = 0; it < itN; ++it) {
        __syncthreads();   // all waves done reading LDS of previous step
        *(short8*)(kLds + krow * 80 + ku * 16) = sk0;
        *(short8*)(kLds + (64 + krow) * 80 + ku * 16) = sk1;
        *(short8*)(vLds + vd * 272 + vu * 16) = sv0;
        *(short8*)(vLds + vd * 272 + 128 + vu * 16) = sv1;
        __syncthreads();

        if (it + 1 < itN) {   // issue next step's loads; land during compute
            const size_t nb = (size_t)(it + 1) << 7;
            sk0 = *(const short8*)(kstage + nb * 64);
            sk1 = *(const short8*)(kstage + nb * 64 + 64 * 64);
            sv0 = *(const short8*)(vstage + nb * 2);
            sv1 = *(const short8*)(vstage + nb * 2 + 128);
            attn_tile128<false>(kLds, vLds, pT, m, q4, qf, ones, 8, 0,
                                O0, O1, mx, ls);
        } else {
            attn_tile128<true>(kLds, vLds, pT, m, q4, qf, ones, sbN_last, limit,
                               O0, O1, mx, ls);
        }
    }

    // ---------------- fused output-projection epilogue --------------------
    // out[t][n] += sum_d O[t][d] * Wout[n][h*32+d]   (atomic across 4 heads)
    __syncthreads();                       // loop done on ALL waves -> reuse LDS
    float*          oLds = (float*)smem;                       // 64 x 36 f32 (144B rows)
    unsigned short* wHi  = (unsigned short*)(smem + 10240);    // 128 x 34 shorts (68B rows)
    unsigned short* wLo  = (unsigned short*)(smem + 18944);    // 128 x 34 shorts

    const int h = bh & 3, b = bh >> 2;
    {   // stash normalized O: row = query (qrow), cols d 0..31
        const float inv = 1.f / ls;
        float* orow = oLds + qrow * 36;
        *(float4*)(orow + q4 * 4)      = make_float4(O0[0] * inv, O0[1] * inv,
                                                     O0[2] * inv, O0[3] * inv);
        *(float4*)(orow + 16 + q4 * 4) = make_float4(O1[0] * inv, O1[1] * inv,
                                                     O1[2] * inv, O1[3] * inv);
    }
    {   // Wout head-slice hi/lo split: n 0..127, k 0..31
        #pragma unroll
        for (int i = 0; i < 16; ++i) {
            const int f = tid + 256 * i;           // 0..4095
            const int n = f >> 5, k = f & 31;
            float w = Wout[n * DM_ + h * 32 + k];
            unsigned short hi_, lo_;
            split_bf(w, hi_, lo_);
            wHi[n * 34 + k] = hi_;
            wLo[n * 34 + k] = lo_;
        }
    }
    __syncthreads();

    // A-frag: row = query (wave*16+m), k = q4*8..+7  (hi/lo split of fp32 O)
    short8 Ah_, Al_;
    {
        const float* ap = oLds + (wave * 16 + m) * 36 + q4 * 8;
        float4 a0 = *(const float4*)(ap);
        float4 a1 = *(const float4*)(ap + 4);
        ushort4 h0, l0, h1, l1;
        split_bf(a0.x, h0.x, l0.x); split_bf(a0.y, h0.y, l0.y);
        split_bf(a0.z, h0.z, l0.z); split_bf(a0.w, h0.w, l0.w);
        split_bf(a1.x, h1.x, l1.x); split_bf(a1.y, h1.y, l1.y);
        split_bf(a1.z, h1.z, l1.z); split_bf(a1.w, h1.w, l1.w);
        Ah_ = short8{(short)h0.x, (short)h0.y, (short)h0.z, (short)h0.w,
                     (short)h1.x, (short)h1.y, (short)h1.z, (short)h1.w};
        Al_ = short8{(short)l0.x, (short)l0.y, (short)l0.z, (short)l0.w,
                     (short)l1.x, (short)l1.y, (short)l1.z, (short)l1.w};
    }

    #pragma unroll
    for (int nb = 0; nb < 8; ++nb) {
        short8 Bh = *(const short8*)(wHi + (nb * 16 + m) * 34 + q4 * 8);
        short8 Bl = *(const short8*)(wLo + (nb * 16 + m) * 34 + q4 * 8);
        floatx4 acc = {0.f, 0.f, 0.f, 0.f};
        acc = __builtin_amdgcn_mfma_f32_16x16x32_bf16(Ah_, Bh, acc, 0, 0, 0);
        acc = __builtin_amdgcn_mfma_f32_16x16x32_bf16(Ah_, Bl, acc, 0, 0, 0);
        acc = __builtin_amdgcn_mfma_f32_16x16x32_bf16(Al_, Bh, acc, 0, 0, 0);
        const int n = nb * 16 + m;                 // C col = lane&15
        #pragma unroll
        for (int reg = 0; reg < 4; ++reg) {        // C row = q4*4+reg = query
            const int t = qt * 64 + wave * 16 + q4 * 4 + reg;
            atomicAdd(out + ((size_t)b * T_ + t) * DM_ + n, acc[reg]);
        }
    }
}

// -------------------------------------------------------------------------
extern "C" void kernel_launch(void* const* d_in, const int* in_sizes, int n_in,
                              void* d_out, int out_size, void* d_ws, size_t ws_size,
                              hipStream_t stream) {
    const float* x    = (const float*)d_in[0];   // (4,4096,128) fp32
    const float* Wqkv = (const float*)d_in[1];   // (384,128)    fp32
    const float* Wout = (const float*)d_in[2];   // (128,128)    fp32
    float* out = (float*)d_out;                  // (4,4096,128) fp32

    // ws layout (bytes): q_bf 4MB | k_bf 4MB | v_t 4MB
    char* ws = (char*)d_ws;
    unsigned short* q_bf  = (unsigned short*)(ws);
    unsigned short* k_bf  = (unsigned short*)(ws + (size_t)4 * 1024 * 1024);
    unsigned short* v_t   = (unsigned short*)(ws + (size_t)8 * 1024 * 1024);

    // zero output: attn epilogue accumulates 4 head-contributions atomically
    hipMemsetAsync(out, 0, (size_t)TOKENS * DM_ * sizeof(float), stream);

    qkv_proj_kernel<<<dim3(TOKENS / 64, 6), 256, 0, stream>>>(x, Wqkv, q_bf, k_bf, v_t);
    attn_mfma_kernel<<<1024, 256, 0, stream>>>(q_bf, k_bf, v_t, Wout, out);
}

// Round 11
// 132.878 us; speedup vs baseline: 1.0346x; 1.0346x over previous
//
#include <hip/hip_runtime.h>
#include <math.h>

// Problem constants (reference: B=4, T=4096, D_MODEL=128, N_HEADS=4, HEAD_DIM=32)
#define B_   4
#define T_   4096
#define DM_  128
#define NH_  4
#define HD_  32
#define TOKENS (B_ * T_)               // 16384

typedef __attribute__((ext_vector_type(8))) short short8;   // 8 bf16 = 4 VGPRs (MFMA A/B frag)
typedef __attribute__((ext_vector_type(4))) float floatx4;  // MFMA C/D frag

__device__ __forceinline__ unsigned short f2bf(float f) {
    union { float f; unsigned int u; } v; v.f = f;
    unsigned int u = v.u;
    u += 0x7fffu + ((u >> 16) & 1u);   // round-to-nearest-even
    return (unsigned short)(u >> 16);
}
__device__ __forceinline__ void split_bf(float v, unsigned short& hi, unsigned short& lo) {
    unsigned short h = f2bf(v);
    float hf = __uint_as_float(((unsigned int)h) << 16);
    hi = h;
    lo = f2bf(v - hf);
}

// LDS row stride for bf16 W tiles: 128 elements + 8 pad = 136 shorts = 272 B.
#define LROW 136

// -------------------------------------------------------------------------
// Kernel 1: QKV projection via MFMA, hi/lo bf16 split, coalesced epilogue.
// (round-6/9 version, unchanged)
// -------------------------------------------------------------------------
__global__ __launch_bounds__(256) void qkv_proj_kernel(
    const float* __restrict__ x, const float* __restrict__ Wqkv,
    unsigned short* __restrict__ q_bf, unsigned short* __restrict__ k_bf,
    unsigned short* __restrict__ v_t)
{
    __shared__ __align__(16) unsigned short whi[64 * LROW];   // 17 KB
    __shared__ __align__(16) unsigned short wlo[64 * LROW];   // 17 KB

    const int tid  = threadIdx.x;
    const int wave = tid >> 6, lane = tid & 63;
    const int m    = lane & 15, q4 = lane >> 4;
    const int m0   = blockIdx.x * 64;
    const int ch   = blockIdx.y;                  // 0..5
    const float scale = 0.2550052509571414f;      // log2(e)/sqrt(32)

    {   // cooperative W chunk split: rows ch*64 .. +63
        const float4* wg = (const float4*)(Wqkv + (size_t)ch * 64 * DM_);
        #pragma unroll
        for (int i = 0; i < 8; ++i) {
            const int f = tid + 256 * i;
            float4 v = wg[f];
            const int row = f >> 5, k4 = f & 31;
            ushort4 h, l;
            split_bf(v.x, h.x, l.x); split_bf(v.y, h.y, l.y);
            split_bf(v.z, h.z, l.z); split_bf(v.w, h.w, l.w);
            *(ushort4*)(whi + row * LROW + k4 * 4) = h;
            *(ushort4*)(wlo + row * LROW + k4 * 4) = l;
        }
    }

    // A-frags direct from global: row m0+wave*16+m, cols ks*32+q4*8..+7
    short8 Ah[4], Al[4];
    {
        const float4* xg = (const float4*)(x + (size_t)(m0 + wave * 16 + m) * DM_);
        #pragma unroll
        for (int ks = 0; ks < 4; ++ks) {
            float4 a = xg[ks * 8 + q4 * 2];
            float4 b = xg[ks * 8 + q4 * 2 + 1];
            ushort4 h0, l0, h1, l1;
            split_bf(a.x, h0.x, l0.x); split_bf(a.y, h0.y, l0.y);
            split_bf(a.z, h0.z, l0.z); split_bf(a.w, h0.w, l0.w);
            split_bf(b.x, h1.x, l1.x); split_bf(b.y, h1.y, l1.y);
            split_bf(b.z, h1.z, l1.z); split_bf(b.w, h1.w, l1.w);
            Ah[ks] = short8{(short)h0.x, (short)h0.y, (short)h0.z, (short)h0.w,
                            (short)h1.x, (short)h1.y, (short)h1.z, (short)h1.w};
            Al[ks] = short8{(short)l0.x, (short)l0.y, (short)l0.z, (short)l0.w,
                            (short)l1.x, (short)l1.y, (short)l1.z, (short)l1.w};
        }
    }
    __syncthreads();

    floatx4 acc[4];
    #pragma unroll
    for (int nb = 0; nb < 4; ++nb) {
        floatx4 a = {0.f, 0.f, 0.f, 0.f};
        #pragma unroll
        for (int ks = 0; ks < 4; ++ks) {
            short8 Bh = *(const short8*)(whi + (nb * 16 + m) * LROW + ks * 32 + q4 * 8);
            short8 Bl = *(const short8*)(wlo + (nb * 16 + m) * LROW + ks * 32 + q4 * 8);
            a = __builtin_amdgcn_mfma_f32_16x16x32_bf16(Ah[ks], Bh, a, 0, 0, 0);
            a = __builtin_amdgcn_mfma_f32_16x16x32_bf16(Ah[ks], Bl, a, 0, 0, 0);
            a = __builtin_amdgcn_mfma_f32_16x16x32_bf16(Al[ks], Bh, a, 0, 0, 0);
        }
        acc[nb] = a;
    }
    __syncthreads();   // all waves done reading whi/wlo -> reuse whi as staging

    // stage C tile as bf16: [64 t][72] for q/k (t-major), [64 n][72] for v (n-major)
    unsigned short* stage = whi;
    const bool isV = (ch >= 4);
    if (isV) {
        #pragma unroll
        for (int nb = 0; nb < 4; ++nb) {
            ushort4 p;
            p.x = f2bf(acc[nb][0]); p.y = f2bf(acc[nb][1]);
            p.z = f2bf(acc[nb][2]); p.w = f2bf(acc[nb][3]);
            *(ushort4*)(stage + (nb * 16 + m) * 72 + wave * 16 + q4 * 4) = p;
        }
    } else {
        const float scl = (ch < 2) ? scale : 1.0f;
        #pragma unroll
        for (int nb = 0; nb < 4; ++nb)
            #pragma unroll
            for (int reg = 0; reg < 4; ++reg)
                stage[(wave * 16 + q4 * 4 + reg) * 72 + nb * 16 + m]
                    = f2bf(acc[nb][reg] * scl);
    }
    __syncthreads();

    // coalesced write-out: 32B (2 x short8) per thread
    const int b    = m0 >> 12;
    const int t0   = m0 & (T_ - 1);
    const int head = tid >> 7;                 // 0..1 (n_local 0..31 / 32..63)
    const int hh   = (ch * 2 + head) & 3;
    const int bh   = b * NH_ + hh;
    const int r    = tid & 127;
    if (isV) {
        const int d = r >> 2, qc = r & 3;      // 32 d-rows x 4 t-chunks of 16
        const unsigned short* sp = stage + (head * 32 + d) * 72 + qc * 16;
        short8 v0 = *(const short8*)(sp);
        short8 v1 = *(const short8*)(sp + 8);
        unsigned short* gp = v_t + ((size_t)bh * HD_ + d) * T_ + t0 + qc * 16;
        *(short8*)(gp)     = v0;
        *(short8*)(gp + 8) = v1;
    } else {
        unsigned short* dst = (ch < 2) ? q_bf : k_bf;
        const int t = r >> 1, half = r & 1;    // 64 t-rows x 2 x 32B halves
        const unsigned short* sp = stage + t * 72 + head * 32 + half * 16;
        short8 v0 = *(const short8*)(sp);
        short8 v1 = *(const short8*)(sp + 8);
        unsigned short* gp = dst + ((size_t)bh * T_ + t0 + t) * HD_ + half * 16;
        *(short8*)(gp)     = v0;
        *(short8*)(gp + 8) = v1;
    }
}

// -------------------------------------------------------------------------
// Kernel 2: bf16 MFMA causal flash attention, S-TRANSPOSED, 128-KEY STEP,
// async-STAGE (T14), ones-MFMA psum — EXACT round-9 logic — with the LDS
// shrunk to EXACTLY 32 KB so 5 blocks/CU fit (was 35328 -> 4 blocks/CU,
// OccupancyPercent 27.5).  Padding replaced by XOR granule swizzles:
//   K  [128 x 64B]:  addr(row,g) = row*64  + ((g ^ (row&3))  << 4), g=0..3
//   V^T[ 32 x 256B]: addr(row,g) = row*256 + ((g ^ (row&15)) << 4), g=0..15
// Both read & write sides derive from the same layout fn (bit-identical
// data); bank analysis: 1KB b128 access spreads 8 accesses/bank over all
// 32 banks = optimal 8 clks on every K/V site.
// -------------------------------------------------------------------------
template<bool LAST>
__device__ __forceinline__ void attn_tile128(
    const char* kLds, const char* vLds, char* pT,
    const int m, const int q4, const short8 qf, const short8 ones,
    const int sbN_in, const int limit,
    floatx4& O0, floatx4& O1, float& mx, float& ls)
{
    const int sbN = LAST ? sbN_in : 8;        // active 16-key sub-frags
    const int kN  = sbN >> 1;                 // active 32-key PV slots

    // S^T = K·Q^T : A = K rows (s), B = Q rows (q).  C[s=q4*4+reg][q=m]
    floatx4 st[8];
    #pragma unroll
    for (int sb = 0; sb < 8; ++sb) {
        if (sb >= sbN) continue;
        short8 kfrag = *(const short8*)(kLds + (sb * 16 + m) * 64
                                        + ((q4 ^ (m & 3)) << 4));
        floatx4 z = {0.f, 0.f, 0.f, 0.f};
        st[sb] = __builtin_amdgcn_mfma_f32_16x16x32_bf16(kfrag, qf, z, 0, 0, 0);
    }

    if (LAST) {   // causal: mask s_local > limit
        #pragma unroll
        for (int sb = 0; sb < 8; ++sb) {
            if (sb >= sbN) continue;
            #pragma unroll
            for (int reg = 0; reg < 4; ++reg)
                if (sb * 16 + q4 * 4 + reg > limit) st[sb][reg] = -INFINITY;
        }
    }

    // per-lane row max over 32 s-values (tree) + 2 cross-quad shuffles
    float fm[8];
    #pragma unroll
    for (int sb = 0; sb < 8; ++sb)
        fm[sb] = (sb < sbN) ? fmaxf(fmaxf(st[sb][0], st[sb][1]),
                                    fmaxf(st[sb][2], st[sb][3]))
                            : -INFINITY;
    float rmax = fmaxf(fmaxf(fmaxf(fm[0], fm[1]), fmaxf(fm[2], fm[3])),
                       fmaxf(fmaxf(fm[4], fm[5]), fmaxf(fm[6], fm[7])));
    rmax = fmaxf(rmax, __shfl_xor(rmax, 16, 64));
    rmax = fmaxf(rmax, __shfl_xor(rmax, 32, 64));

    const float mn = fmaxf(mx, rmax);
    const float alpha = __builtin_amdgcn_exp2f(mx - mn);   // exp2(-inf)=0 first step
    mx = mn;

    // p = exp2(s - mn); pack hi16 (round-half-up) via v_perm; b64 writes
    // swizzled 16B granule: g = (2*sb + (q4>>1)) ^ m, half = q4&1
    #pragma unroll
    for (int sb = 0; sb < 8; ++sb) {
        if (sb >= sbN) continue;
        float p0 = __builtin_amdgcn_exp2f(st[sb][0] - mn);
        float p1 = __builtin_amdgcn_exp2f(st[sb][1] - mn);
        float p2 = __builtin_amdgcn_exp2f(st[sb][2] - mn);
        float p3 = __builtin_amdgcn_exp2f(st[sb][3] - mn);
        unsigned u0 = __float_as_uint(p0) + 0x8000u;
        unsigned u1 = __float_as_uint(p1) + 0x8000u;
        unsigned u2 = __float_as_uint(p2) + 0x8000u;
        unsigned u3 = __float_as_uint(p3) + 0x8000u;
        uint2 pk;
        pk.x = __builtin_amdgcn_perm(u1, u0, 0x07060302);  // [bf(p0) | bf(p1)<<16]
        pk.y = __builtin_amdgcn_perm(u3, u2, 0x07060302);
        *(uint2*)(pT + ((((2 * sb + (q4 >> 1)) ^ m) << 4) + (q4 & 1) * 8)) = pk;
    }
    #pragma unroll
    for (int reg = 0; reg < 4; ++reg) { O0[reg] *= alpha; O1[reg] *= alpha; }

    // drain wave-internal P^T writes before cross-lane B-frag reads
    __asm__ volatile("s_waitcnt lgkmcnt(0)" ::: "memory");
    __builtin_amdgcn_sched_barrier(0);   // rule #18: keep MFMA below the fence

    // O^T += V^T · P^T ; row-sum of P via ones-MFMA (C row = col-sum of B):
    // ps[reg] = sum_k P^T[k][q=m], identical across regs -> no shuffles.
    floatx4 ps = {0.f, 0.f, 0.f, 0.f};
    #pragma unroll
    for (int ks = 0; ks < 4; ++ks) {
        if (ks >= kN) continue;
        short8 bfrag = *(const short8*)(pT + (((ks * 4 + q4) ^ m) << 4));
        short8 va = *(const short8*)(vLds + m * 256
                                     + (((ks * 4 + q4) ^ m) << 4));
        short8 vb = *(const short8*)(vLds + (16 + m) * 256
                                     + (((ks * 4 + q4) ^ m) << 4));
        O0 = __builtin_amdgcn_mfma_f32_16x16x32_bf16(va, bfrag, O0, 0, 0, 0);
        O1 = __builtin_amdgcn_mfma_f32_16x16x32_bf16(vb, bfrag, O1, 0, 0, 0);
        ps = __builtin_amdgcn_mfma_f32_16x16x32_bf16(ones, bfrag, ps, 0, 0, 0);
    }
    ls = ls * alpha + ps[0];
}

__global__ __launch_bounds__(256, 5) void attn_mfma_kernel(
    const unsigned short* __restrict__ qb, const unsigned short* __restrict__ kb,
    const unsigned short* __restrict__ vtb, float* __restrict__ og)
{
    // LDS (swizzled, no padding): K 8192 | V^T 8192 | P^T 4x4096 = 32768 B
    __shared__ __align__(16) char smem[32768];
    char* kLds = smem;
    char* vLds = smem + 8192;
    const int tid  = threadIdx.x;
    const int wave = tid >> 6, lane = tid & 63;
    const int m    = lane & 15, q4 = lane >> 4;
    char* pT = smem + 16384 + wave * 4096 + m * 256;   // this lane's P^T row base

    // Dispatch swizzle: XCD-locality (2 heads per XCD) + per-CU qt balance.
    const int pid = blockIdx.x;
    const int xcd = pid & 7;
    const int r_  = pid >> 3;
    const int bh  = xcd * 2 + (r_ & 1);
    const int j_  = r_ >> 1;
    const int a_  = j_ & 15, k_ = j_ >> 4;
    const int qt  = (k_ == 0) ? a_ : (k_ == 1) ? 63 - a_
                  : (k_ == 2) ? 32 + a_ : 31 - a_;

    const size_t qkbase = (size_t)bh * T_ * HD_;
    const char* kg = (const char*)(kb + qkbase);
    const char* vg = (const char*)(vtb + qkbase);

    // Q B-fragment: row qt*64+wave*16+m, k-bytes q4*16 (Q pre-scaled, exp2 domain)
    short8 qf = *(const short8*)((const char*)(qb + qkbase)
                 + (size_t)(qt * 64 + wave * 16 + m) * 64 + q4 * 16);
    const int qrow = wave * 16 + m;        // query row within the 64-block

    const short8 ones = short8{(short)0x3F80, (short)0x3F80, (short)0x3F80,
                               (short)0x3F80, (short)0x3F80, (short)0x3F80,
                               (short)0x3F80, (short)0x3F80};   // bf16 1.0 x8

    floatx4 O0 = {0.f, 0.f, 0.f, 0.f}, O1 = {0.f, 0.f, 0.f, 0.f};
    float mx = -INFINITY, ls = 0.f;

    const int itN      = (qt >> 1) + 1;            // 128-key steps
    const int sbN_last = (qt & 1) ? 8 : 4;         // active sub-frags on diagonal
    const int limit    = ((qt & 1) << 6) + qrow;   // causal mask threshold

    // async-STAGE: per-thread staging addresses + prologue load of step 0
    const int krow = tid >> 2, ku = tid & 3;
    const int vd = tid >> 3, vu = tid & 7;
    const char* kstage = kg + (size_t)krow * 64 + ku * 16;
    const char* vstage = vg + (size_t)vd * (T_ * 2) + vu * 16;

    // swizzled LDS destinations (constant per thread)
    const int kdst = krow * 64 + ((ku ^ (krow & 3)) << 4);
    const int vdst = vd * 256 + ((vu ^ (vd & 15)) << 4);

    short8 sk0 = *(const short8*)(kstage);
    short8 sk1 = *(const short8*)(kstage + 64 * 64);
    short8 sv0 = *(const short8*)(vstage);
    short8 sv1 = *(const short8*)(vstage + 128);

    for (int it = 0; it < itN; ++it) {
        __syncthreads();   // all waves done reading LDS of previous step
        *(short8*)(kLds + kdst) = sk0;
        *(short8*)(kLds + 64 * 64 + kdst) = sk1;       // row 64+krow: same xor key
        *(short8*)(vLds + vdst) = sv0;
        *(short8*)(vLds + (vdst ^ 128)) = sv1;         // granule vu+8 = g^8
        __syncthreads();

        if (it + 1 < itN) {   // issue next step's loads; land during compute
            const size_t nb = (size_t)(it + 1) << 7;
            sk0 = *(const short8*)(kstage + nb * 64);
            sk1 = *(const short8*)(kstage + nb * 64 + 64 * 64);
            sv0 = *(const short8*)(vstage + nb * 2);
            sv1 = *(const short8*)(vstage + nb * 2 + 128);
            attn_tile128<false>(kLds, vLds, pT, m, q4, qf, ones, 8, 0,
                                O0, O1, mx, ls);
        } else {
            attn_tile128<true>(kLds, vLds, pT, m, q4, qf, ones, sbN_last, limit,
                               O0, O1, mx, ls);
        }
    }

    // epilogue: O^T[d][q=m] -> lane holds d = q4*4+reg (+16);  t = per-lane row
    const float inv = 1.f / ls;
    const int b = bh >> 2, h = bh & 3;
    const int t = qt * 64 + qrow;
    float* orow = og + (((size_t)b * T_ + t) * NH_ + h) * HD_;
    *(float4*)(orow + q4 * 4)      = make_float4(O0[0] * inv, O0[1] * inv,
                                                 O0[2] * inv, O0[3] * inv);
    *(float4*)(orow + 16 + q4 * 4) = make_float4(O1[0] * inv, O1[1] * inv,
                                                 O1[2] * inv, O1[3] * inv);
}

// -------------------------------------------------------------------------
// Kernel 3: output projection via MFMA, hi/lo bf16 split.  (round-9 version)
// -------------------------------------------------------------------------
__global__ __launch_bounds__(256) void out_proj_kernel(
    const float* __restrict__ a, const float* __restrict__ Wout,
    float* __restrict__ out)
{
    __shared__ __align__(16) unsigned short whi[64 * LROW];
    __shared__ __align__(16) unsigned short wlo[64 * LROW];

    const int tid  = threadIdx.x;
    const int wave = tid >> 6, lane = tid & 63;
    const int m    = lane & 15, q4 = lane >> 4;
    const int m0   = blockIdx.x * 64;
    const int ch   = blockIdx.y;                  // 0..1

    {   // cooperative W chunk split
        const float4* wg = (const float4*)(Wout + (size_t)ch * 64 * DM_);
        #pragma unroll
        for (int i = 0; i < 8; ++i) {
            const int f = tid + 256 * i;
            float4 v = wg[f];
            const int row = f >> 5, k4 = f & 31;
            ushort4 h, l;
            split_bf(v.x, h.x, l.x); split_bf(v.y, h.y, l.y);
            split_bf(v.z, h.z, l.z); split_bf(v.w, h.w, l.w);
            *(ushort4*)(whi + row * LROW + k4 * 4) = h;
            *(ushort4*)(wlo + row * LROW + k4 * 4) = l;
        }
    }

    short8 Ah[4], Al[4];
    {
        const float4* xg = (const float4*)(a + (size_t)(m0 + wave * 16 + m) * DM_);
        #pragma unroll
        for (int ks = 0; ks < 4; ++ks) {
            float4 av = xg[ks * 8 + q4 * 2];
            float4 bv = xg[ks * 8 + q4 * 2 + 1];
            ushort4 h0, l0, h1, l1;
            split_bf(av.x, h0.x, l0.x); split_bf(av.y, h0.y, l0.y);
            split_bf(av.z, h0.z, l0.z); split_bf(av.w, h0.w, l0.w);
            split_bf(bv.x, h1.x, l1.x); split_bf(bv.y, h1.y, l1.y);
            split_bf(bv.z, h1.z, l1.z); split_bf(bv.w, h1.w, l1.w);
            Ah[ks] = short8{(short)h0.x, (short)h0.y, (short)h0.z, (short)h0.w,
                            (short)h1.x, (short)h1.y, (short)h1.z, (short)h1.w};
            Al[ks] = short8{(short)l0.x, (short)l0.y, (short)l0.z, (short)l0.w,
                            (short)l1.x, (short)l1.y, (short)l1.z, (short)l1.w};
        }
    }
    __syncthreads();

    #pragma unroll
    for (int nb = 0; nb < 4; ++nb) {
        floatx4 acc = {0.f, 0.f, 0.f, 0.f};
        #pragma unroll
        for (int ks = 0; ks < 4; ++ks) {
            short8 Bh = *(const short8*)(whi + (nb * 16 + m) * LROW + ks * 32 + q4 * 8);
            short8 Bl = *(const short8*)(wlo + (nb * 16 + m) * LROW + ks * 32 + q4 * 8);
            acc = __builtin_amdgcn_mfma_f32_16x16x32_bf16(Ah[ks], Bh, acc, 0, 0, 0);
            acc = __builtin_amdgcn_mfma_f32_16x16x32_bf16(Ah[ks], Bl, acc, 0, 0, 0);
            acc = __builtin_amdgcn_mfma_f32_16x16x32_bf16(Al[ks], Bh, acc, 0, 0, 0);
        }
        const int n = ch * 64 + nb * 16 + m;
        const int tok0 = m0 + wave * 16 + q4 * 4;
        #pragma unroll
        for (int reg = 0; reg < 4; ++reg)
            out[(size_t)(tok0 + reg) * DM_ + n] = acc[reg];
    }
}

// -------------------------------------------------------------------------
extern "C" void kernel_launch(void* const* d_in, const int* in_sizes, int n_in,
                              void* d_out, int out_size, void* d_ws, size_t ws_size,
                              hipStream_t stream) {
    const float* x    = (const float*)d_in[0];   // (4,4096,128) fp32
    const float* Wqkv = (const float*)d_in[1];   // (384,128)    fp32
    const float* Wout = (const float*)d_in[2];   // (128,128)    fp32
    float* out = (float*)d_out;                  // (4,4096,128) fp32

    // ws layout (bytes): q_bf 4MB | k_bf 4MB | v_t 4MB | att_ws fp32 8MB
    char* ws = (char*)d_ws;
    unsigned short* q_bf  = (unsigned short*)(ws);
    unsigned short* k_bf  = (unsigned short*)(ws + (size_t)4 * 1024 * 1024);
    unsigned short* v_t   = (unsigned short*)(ws + (size_t)8 * 1024 * 1024);
    float*          att_ws = (float*)(ws + (size_t)12 * 1024 * 1024);

    qkv_proj_kernel<<<dim3(TOKENS / 64, 6), 256, 0, stream>>>(x, Wqkv, q_bf, k_bf, v_t);
    attn_mfma_kernel<<<1024, 256, 0, stream>>>(q_bf, k_bf, v_t, att_ws);
    out_proj_kernel<<<dim3(TOKENS / 64, 2), 256, 0, stream>>>(att_ws, Wout, out);
}

// Round 12
// 129.005 us; speedup vs baseline: 1.0657x; 1.0300x over previous
//
#include <hip/hip_runtime.h>
#include <math.h>

// Problem constants (reference: B=4, T=4096, D_MODEL=128, N_HEADS=4, HEAD_DIM=32)
#define B_   4
#define T_   4096
#define DM_  128
#define NH_  4
#define HD_  32
#define TOKENS (B_ * T_)               // 16384

typedef __attribute__((ext_vector_type(8))) short short8;   // 8 bf16 = 4 VGPRs (MFMA A/B frag)
typedef __attribute__((ext_vector_type(4))) float floatx4;  // MFMA C/D frag

__device__ __forceinline__ unsigned short f2bf(float f) {
    union { float f; unsigned int u; } v; v.f = f;
    unsigned int u = v.u;
    u += 0x7fffu + ((u >> 16) & 1u);   // round-to-nearest-even
    return (unsigned short)(u >> 16);
}
__device__ __forceinline__ void split_bf(float v, unsigned short& hi, unsigned short& lo) {
    unsigned short h = f2bf(v);
    float hf = __uint_as_float(((unsigned int)h) << 16);
    hi = h;
    lo = f2bf(v - hf);
}

// LDS row stride for bf16 W tiles: 128 elements + 8 pad = 136 shorts = 272 B.
#define LROW 136

// -------------------------------------------------------------------------
// Kernel 1: QKV projection via MFMA, hi/lo bf16 split, coalesced epilogue.
// (round-6/9 version, unchanged)
// -------------------------------------------------------------------------
__global__ __launch_bounds__(256) void qkv_proj_kernel(
    const float* __restrict__ x, const float* __restrict__ Wqkv,
    unsigned short* __restrict__ q_bf, unsigned short* __restrict__ k_bf,
    unsigned short* __restrict__ v_t)
{
    __shared__ __align__(16) unsigned short whi[64 * LROW];   // 17 KB
    __shared__ __align__(16) unsigned short wlo[64 * LROW];   // 17 KB

    const int tid  = threadIdx.x;
    const int wave = tid >> 6, lane = tid & 63;
    const int m    = lane & 15, q4 = lane >> 4;
    const int m0   = blockIdx.x * 64;
    const int ch   = blockIdx.y;                  // 0..5
    const float scale = 0.2550052509571414f;      // log2(e)/sqrt(32)

    {   // cooperative W chunk split: rows ch*64 .. +63
        const float4* wg = (const float4*)(Wqkv + (size_t)ch * 64 * DM_);
        #pragma unroll
        for (int i = 0; i < 8; ++i) {
            const int f = tid + 256 * i;
            float4 v = wg[f];
            const int row = f >> 5, k4 = f & 31;
            ushort4 h, l;
            split_bf(v.x, h.x, l.x); split_bf(v.y, h.y, l.y);
            split_bf(v.z, h.z, l.z); split_bf(v.w, h.w, l.w);
            *(ushort4*)(whi + row * LROW + k4 * 4) = h;
            *(ushort4*)(wlo + row * LROW + k4 * 4) = l;
        }
    }

    // A-frags direct from global: row m0+wave*16+m, cols ks*32+q4*8..+7
    short8 Ah[4], Al[4];
    {
        const float4* xg = (const float4*)(x + (size_t)(m0 + wave * 16 + m) * DM_);
        #pragma unroll
        for (int ks = 0; ks < 4; ++ks) {
            float4 a = xg[ks * 8 + q4 * 2];
            float4 b = xg[ks * 8 + q4 * 2 + 1];
            ushort4 h0, l0, h1, l1;
            split_bf(a.x, h0.x, l0.x); split_bf(a.y, h0.y, l0.y);
            split_bf(a.z, h0.z, l0.z); split_bf(a.w, h0.w, l0.w);
            split_bf(b.x, h1.x, l1.x); split_bf(b.y, h1.y, l1.y);
            split_bf(b.z, h1.z, l1.z); split_bf(b.w, h1.w, l1.w);
            Ah[ks] = short8{(short)h0.x, (short)h0.y, (short)h0.z, (short)h0.w,
                            (short)h1.x, (short)h1.y, (short)h1.z, (short)h1.w};
            Al[ks] = short8{(short)l0.x, (short)l0.y, (short)l0.z, (short)l0.w,
                            (short)l1.x, (short)l1.y, (short)l1.z, (short)l1.w};
        }
    }
    __syncthreads();

    floatx4 acc[4];
    #pragma unroll
    for (int nb = 0; nb < 4; ++nb) {
        floatx4 a = {0.f, 0.f, 0.f, 0.f};
        #pragma unroll
        for (int ks = 0; ks < 4; ++ks) {
            short8 Bh = *(const short8*)(whi + (nb * 16 + m) * LROW + ks * 32 + q4 * 8);
            short8 Bl = *(const short8*)(wlo + (nb * 16 + m) * LROW + ks * 32 + q4 * 8);
            a = __builtin_amdgcn_mfma_f32_16x16x32_bf16(Ah[ks], Bh, a, 0, 0, 0);
            a = __builtin_amdgcn_mfma_f32_16x16x32_bf16(Ah[ks], Bl, a, 0, 0, 0);
            a = __builtin_amdgcn_mfma_f32_16x16x32_bf16(Al[ks], Bh, a, 0, 0, 0);
        }
        acc[nb] = a;
    }
    __syncthreads();   // all waves done reading whi/wlo -> reuse whi as staging

    // stage C tile as bf16: [64 t][72] for q/k (t-major), [64 n][72] for v (n-major)
    unsigned short* stage = whi;
    const bool isV = (ch >= 4);
    if (isV) {
        #pragma unroll
        for (int nb = 0; nb < 4; ++nb) {
            ushort4 p;
            p.x = f2bf(acc[nb][0]); p.y = f2bf(acc[nb][1]);
            p.z = f2bf(acc[nb][2]); p.w = f2bf(acc[nb][3]);
            *(ushort4*)(stage + (nb * 16 + m) * 72 + wave * 16 + q4 * 4) = p;
        }
    } else {
        const float scl = (ch < 2) ? scale : 1.0f;
        #pragma unroll
        for (int nb = 0; nb < 4; ++nb)
            #pragma unroll
            for (int reg = 0; reg < 4; ++reg)
                stage[(wave * 16 + q4 * 4 + reg) * 72 + nb * 16 + m]
                    = f2bf(acc[nb][reg] * scl);
    }
    __syncthreads();

    // coalesced write-out: 32B (2 x short8) per thread
    const int b    = m0 >> 12;
    const int t0   = m0 & (T_ - 1);
    const int head = tid >> 7;                 // 0..1 (n_local 0..31 / 32..63)
    const int hh   = (ch * 2 + head) & 3;
    const int bh   = b * NH_ + hh;
    const int r    = tid & 127;
    if (isV) {
        const int d = r >> 2, qc = r & 3;      // 32 d-rows x 4 t-chunks of 16
        const unsigned short* sp = stage + (head * 32 + d) * 72 + qc * 16;
        short8 v0 = *(const short8*)(sp);
        short8 v1 = *(const short8*)(sp + 8);
        unsigned short* gp = v_t + ((size_t)bh * HD_ + d) * T_ + t0 + qc * 16;
        *(short8*)(gp)     = v0;
        *(short8*)(gp + 8) = v1;
    } else {
        unsigned short* dst = (ch < 2) ? q_bf : k_bf;
        const int t = r >> 1, half = r & 1;    // 64 t-rows x 2 x 32B halves
        const unsigned short* sp = stage + t * 72 + head * 32 + half * 16;
        short8 v0 = *(const short8*)(sp);
        short8 v1 = *(const short8*)(sp + 8);
        unsigned short* gp = dst + ((size_t)bh * T_ + t0 + t) * HD_ + half * 16;
        *(short8*)(gp)     = v0;
        *(short8*)(gp + 8) = v1;
    }
}

// -------------------------------------------------------------------------
// Kernel 2: bf16 MFMA causal flash attention, S-TRANSPOSED, 128-KEY STEP,
// async-STAGE (T14), ones-MFMA psum, 32 KB swizzled LDS (round-11 layout).
// FIX vs round 11: __launch_bounds__(256, 4) — the (256,5) hint capped the
// allocator at 48 VGPR and the live set (st[8]+O+staging ~70 regs) spilled
// to scratch: FETCH 6.2->14.9MB, WRITE 8.2->35.3MB of HBM spill traffic.
// With (256,4) the allocator gets its natural ~64 VGPR (no spills) while
// the HW can still co-schedule 5 blocks/CU (LDS 32768*5 = 160KB exactly;
// 64 VGPR permits 8 waves/SIMD >> 20 waves/CU).
//   K  [128 x 64B]:  addr(row,g) = row*64  + ((g ^ (row&3))  << 4)
//   V^T[ 32 x 256B]: addr(row,g) = row*256 + ((g ^ (row&15)) << 4)
// -------------------------------------------------------------------------
template<bool LAST>
__device__ __forceinline__ void attn_tile128(
    const char* kLds, const char* vLds, char* pT,
    const int m, const int q4, const short8 qf, const short8 ones,
    const int sbN_in, const int limit,
    floatx4& O0, floatx4& O1, float& mx, float& ls)
{
    const int sbN = LAST ? sbN_in : 8;        // active 16-key sub-frags
    const int kN  = sbN >> 1;                 // active 32-key PV slots

    // S^T = K·Q^T : A = K rows (s), B = Q rows (q).  C[s=q4*4+reg][q=m]
    floatx4 st[8];
    #pragma unroll
    for (int sb = 0; sb < 8; ++sb) {
        if (sb >= sbN) continue;
        short8 kfrag = *(const short8*)(kLds + (sb * 16 + m) * 64
                                        + ((q4 ^ (m & 3)) << 4));
        floatx4 z = {0.f, 0.f, 0.f, 0.f};
        st[sb] = __builtin_amdgcn_mfma_f32_16x16x32_bf16(kfrag, qf, z, 0, 0, 0);
    }

    if (LAST) {   // causal: mask s_local > limit
        #pragma unroll
        for (int sb = 0; sb < 8; ++sb) {
            if (sb >= sbN) continue;
            #pragma unroll
            for (int reg = 0; reg < 4; ++reg)
                if (sb * 16 + q4 * 4 + reg > limit) st[sb][reg] = -INFINITY;
        }
    }

    // per-lane row max over 32 s-values (tree) + 2 cross-quad shuffles
    float fm[8];
    #pragma unroll
    for (int sb = 0; sb < 8; ++sb)
        fm[sb] = (sb < sbN) ? fmaxf(fmaxf(st[sb][0], st[sb][1]),
                                    fmaxf(st[sb][2], st[sb][3]))
                            : -INFINITY;
    float rmax = fmaxf(fmaxf(fmaxf(fm[0], fm[1]), fmaxf(fm[2], fm[3])),
                       fmaxf(fmaxf(fm[4], fm[5]), fmaxf(fm[6], fm[7])));
    rmax = fmaxf(rmax, __shfl_xor(rmax, 16, 64));
    rmax = fmaxf(rmax, __shfl_xor(rmax, 32, 64));

    const float mn = fmaxf(mx, rmax);
    const float alpha = __builtin_amdgcn_exp2f(mx - mn);   // exp2(-inf)=0 first step
    mx = mn;

    // p = exp2(s - mn); pack hi16 (round-half-up) via v_perm; b64 writes
    // swizzled 16B granule: g = (2*sb + (q4>>1)) ^ m, half = q4&1
    #pragma unroll
    for (int sb = 0; sb < 8; ++sb) {
        if (sb >= sbN) continue;
        float p0 = __builtin_amdgcn_exp2f(st[sb][0] - mn);
        float p1 = __builtin_amdgcn_exp2f(st[sb][1] - mn);
        float p2 = __builtin_amdgcn_exp2f(st[sb][2] - mn);
        float p3 = __builtin_amdgcn_exp2f(st[sb][3] - mn);
        unsigned u0 = __float_as_uint(p0) + 0x8000u;
        unsigned u1 = __float_as_uint(p1) + 0x8000u;
        unsigned u2 = __float_as_uint(p2) + 0x8000u;
        unsigned u3 = __float_as_uint(p3) + 0x8000u;
        uint2 pk;
        pk.x = __builtin_amdgcn_perm(u1, u0, 0x07060302);  // [bf(p0) | bf(p1)<<16]
        pk.y = __builtin_amdgcn_perm(u3, u2, 0x07060302);
        *(uint2*)(pT + ((((2 * sb + (q4 >> 1)) ^ m) << 4) + (q4 & 1) * 8)) = pk;
    }
    #pragma unroll
    for (int reg = 0; reg < 4; ++reg) { O0[reg] *= alpha; O1[reg] *= alpha; }

    // drain wave-internal P^T writes before cross-lane B-frag reads
    __asm__ volatile("s_waitcnt lgkmcnt(0)" ::: "memory");
    __builtin_amdgcn_sched_barrier(0);   // rule #18: keep MFMA below the fence

    // O^T += V^T · P^T ; row-sum of P via ones-MFMA (C row = col-sum of B):
    // ps[reg] = sum_k P^T[k][q=m], identical across regs -> no shuffles.
    floatx4 ps = {0.f, 0.f, 0.f, 0.f};
    #pragma unroll
    for (int ks = 0; ks < 4; ++ks) {
        if (ks >= kN) continue;
        short8 bfrag = *(const short8*)(pT + (((ks * 4 + q4) ^ m) << 4));
        short8 va = *(const short8*)(vLds + m * 256
                                     + (((ks * 4 + q4) ^ m) << 4));
        short8 vb = *(const short8*)(vLds + (16 + m) * 256
                                     + (((ks * 4 + q4) ^ m) << 4));
        O0 = __builtin_amdgcn_mfma_f32_16x16x32_bf16(va, bfrag, O0, 0, 0, 0);
        O1 = __builtin_amdgcn_mfma_f32_16x16x32_bf16(vb, bfrag, O1, 0, 0, 0);
        ps = __builtin_amdgcn_mfma_f32_16x16x32_bf16(ones, bfrag, ps, 0, 0, 0);
    }
    ls = ls * alpha + ps[0];
}

__global__ __launch_bounds__(256, 4) void attn_mfma_kernel(
    const unsigned short* __restrict__ qb, const unsigned short* __restrict__ kb,
    const unsigned short* __restrict__ vtb, float* __restrict__ og)
{
    // LDS (swizzled, no padding): K 8192 | V^T 8192 | P^T 4x4096 = 32768 B
    __shared__ __align__(16) char smem[32768];
    char* kLds = smem;
    char* vLds = smem + 8192;
    const int tid  = threadIdx.x;
    const int wave = tid >> 6, lane = tid & 63;
    const int m    = lane & 15, q4 = lane >> 4;
    char* pT = smem + 16384 + wave * 4096 + m * 256;   // this lane's P^T row base

    // Dispatch swizzle: XCD-locality (2 heads per XCD) + per-CU qt balance.
    const int pid = blockIdx.x;
    const int xcd = pid & 7;
    const int r_  = pid >> 3;
    const int bh  = xcd * 2 + (r_ & 1);
    const int j_  = r_ >> 1;
    const int a_  = j_ & 15, k_ = j_ >> 4;
    const int qt  = (k_ == 0) ? a_ : (k_ == 1) ? 63 - a_
                  : (k_ == 2) ? 32 + a_ : 31 - a_;

    const size_t qkbase = (size_t)bh * T_ * HD_;
    const char* kg = (const char*)(kb + qkbase);
    const char* vg = (const char*)(vtb + qkbase);

    // Q B-fragment: row qt*64+wave*16+m, k-bytes q4*16 (Q pre-scaled, exp2 domain)
    short8 qf = *(const short8*)((const char*)(qb + qkbase)
                 + (size_t)(qt * 64 + wave * 16 + m) * 64 + q4 * 16);
    const int qrow = wave * 16 + m;        // query row within the 64-block

    const short8 ones = short8{(short)0x3F80, (short)0x3F80, (short)0x3F80,
                               (short)0x3F80, (short)0x3F80, (short)0x3F80,
                               (short)0x3F80, (short)0x3F80};   // bf16 1.0 x8

    floatx4 O0 = {0.f, 0.f, 0.f, 0.f}, O1 = {0.f, 0.f, 0.f, 0.f};
    float mx = -INFINITY, ls = 0.f;

    const int itN      = (qt >> 1) + 1;            // 128-key steps
    const int sbN_last = (qt & 1) ? 8 : 4;         // active sub-frags on diagonal
    const int limit    = ((qt & 1) << 6) + qrow;   // causal mask threshold

    // async-STAGE: per-thread staging addresses + prologue load of step 0
    const int krow = tid >> 2, ku = tid & 3;
    const int vd = tid >> 3, vu = tid & 7;
    const char* kstage = kg + (size_t)krow * 64 + ku * 16;
    const char* vstage = vg + (size_t)vd * (T_ * 2) + vu * 16;

    // swizzled LDS destinations (constant per thread)
    const int kdst = krow * 64 + ((ku ^ (krow & 3)) << 4);
    const int vdst = vd * 256 + ((vu ^ (vd & 15)) << 4);

    short8 sk0 = *(const short8*)(kstage);
    short8 sk1 = *(const short8*)(kstage + 64 * 64);
    short8 sv0 = *(const short8*)(vstage);
    short8 sv1 = *(const short8*)(vstage + 128);

    for (int it = 0; it < itN; ++it) {
        __syncthreads();   // all waves done reading LDS of previous step
        *(short8*)(kLds + kdst) = sk0;
        *(short8*)(kLds + 64 * 64 + kdst) = sk1;       // row 64+krow: same xor key
        *(short8*)(vLds + vdst) = sv0;
        *(short8*)(vLds + (vdst ^ 128)) = sv1;         // granule vu+8 = g^8
        __syncthreads();

        if (it + 1 < itN) {   // issue next step's loads; land during compute
            const size_t nb = (size_t)(it + 1) << 7;
            sk0 = *(const short8*)(kstage + nb * 64);
            sk1 = *(const short8*)(kstage + nb * 64 + 64 * 64);
            sv0 = *(const short8*)(vstage + nb * 2);
            sv1 = *(const short8*)(vstage + nb * 2 + 128);
            attn_tile128<false>(kLds, vLds, pT, m, q4, qf, ones, 8, 0,
                                O0, O1, mx, ls);
        } else {
            attn_tile128<true>(kLds, vLds, pT, m, q4, qf, ones, sbN_last, limit,
                               O0, O1, mx, ls);
        }
    }

    // epilogue: O^T[d][q=m] -> lane holds d = q4*4+reg (+16);  t = per-lane row
    const float inv = 1.f / ls;
    const int b = bh >> 2, h = bh & 3;
    const int t = qt * 64 + qrow;
    float* orow = og + (((size_t)b * T_ + t) * NH_ + h) * HD_;
    *(float4*)(orow + q4 * 4)      = make_float4(O0[0] * inv, O0[1] * inv,
                                                 O0[2] * inv, O0[3] * inv);
    *(float4*)(orow + 16 + q4 * 4) = make_float4(O1[0] * inv, O1[1] * inv,
                                                 O1[2] * inv, O1[3] * inv);
}

// -------------------------------------------------------------------------
// Kernel 3: output projection via MFMA, hi/lo bf16 split.  (round-9 version)
// -------------------------------------------------------------------------
__global__ __launch_bounds__(256) void out_proj_kernel(
    const float* __restrict__ a, const float* __restrict__ Wout,
    float* __restrict__ out)
{
    __shared__ __align__(16) unsigned short whi[64 * LROW];
    __shared__ __align__(16) unsigned short wlo[64 * LROW];

    const int tid  = threadIdx.x;
    const int wave = tid >> 6, lane = tid & 63;
    const int m    = lane & 15, q4 = lane >> 4;
    const int m0   = blockIdx.x * 64;
    const int ch   = blockIdx.y;                  // 0..1

    {   // cooperative W chunk split
        const float4* wg = (const float4*)(Wout + (size_t)ch * 64 * DM_);
        #pragma unroll
        for (int i = 0; i < 8; ++i) {
            const int f = tid + 256 * i;
            float4 v = wg[f];
            const int row = f >> 5, k4 = f & 31;
            ushort4 h, l;
            split_bf(v.x, h.x, l.x); split_bf(v.y, h.y, l.y);
            split_bf(v.z, h.z, l.z); split_bf(v.w, h.w, l.w);
            *(ushort4*)(whi + row * LROW + k4 * 4) = h;
            *(ushort4*)(wlo + row * LROW + k4 * 4) = l;
        }
    }

    short8 Ah[4], Al[4];
    {
        const float4* xg = (const float4*)(a + (size_t)(m0 + wave * 16 + m) * DM_);
        #pragma unroll
        for (int ks = 0; ks < 4; ++ks) {
            float4 av = xg[ks * 8 + q4 * 2];
            float4 bv = xg[ks * 8 + q4 * 2 + 1];
            ushort4 h0, l0, h1, l1;
            split_bf(av.x, h0.x, l0.x); split_bf(av.y, h0.y, l0.y);
            split_bf(av.z, h0.z, l0.z); split_bf(av.w, h0.w, l0.w);
            split_bf(bv.x, h1.x, l1.x); split_bf(bv.y, h1.y, l1.y);
            split_bf(bv.z, h1.z, l1.z); split_bf(bv.w, h1.w, l1.w);
            Ah[ks] = short8{(short)h0.x, (short)h0.y, (short)h0.z, (short)h0.w,
                            (short)h1.x, (short)h1.y, (short)h1.z, (short)h1.w};
            Al[ks] = short8{(short)l0.x, (short)l0.y, (short)l0.z, (short)l0.w,
                            (short)l1.x, (short)l1.y, (short)l1.z, (short)l1.w};
        }
    }
    __syncthreads();

    #pragma unroll
    for (int nb = 0; nb < 4; ++nb) {
        floatx4 acc = {0.f, 0.f, 0.f, 0.f};
        #pragma unroll
        for (int ks = 0; ks < 4; ++ks) {
            short8 Bh = *(const short8*)(whi + (nb * 16 + m) * LROW + ks * 32 + q4 * 8);
            short8 Bl = *(const short8*)(wlo + (nb * 16 + m) * LROW + ks * 32 + q4 * 8);
            acc = __builtin_amdgcn_mfma_f32_16x16x32_bf16(Ah[ks], Bh, acc, 0, 0, 0);
            acc = __builtin_amdgcn_mfma_f32_16x16x32_bf16(Ah[ks], Bl, acc, 0, 0, 0);
            acc = __builtin_amdgcn_mfma_f32_16x16x32_bf16(Al[ks], Bh, acc, 0, 0, 0);
        }
        const int n = ch * 64 + nb * 16 + m;
        const int tok0 = m0 + wave * 16 + q4 * 4;
        #pragma unroll
        for (int reg = 0; reg < 4; ++reg)
            out[(size_t)(tok0 + reg) * DM_ + n] = acc[reg];
    }
}

// -------------------------------------------------------------------------
extern "C" void kernel_launch(void* const* d_in, const int* in_sizes, int n_in,
                              void* d_out, int out_size, void* d_ws, size_t ws_size,
                              hipStream_t stream) {
    const float* x    = (const float*)d_in[0];   // (4,4096,128) fp32
    const float* Wqkv = (const float*)d_in[1];   // (384,128)    fp32
    const float* Wout = (const float*)d_in[2];   // (128,128)    fp32
    float* out = (float*)d_out;                  // (4,4096,128) fp32

    // ws layout (bytes): q_bf 4MB | k_bf 4MB | v_t 4MB | att_ws fp32 8MB
    char* ws = (char*)d_ws;
    unsigned short* q_bf  = (unsigned short*)(ws);
    unsigned short* k_bf  = (unsigned short*)(ws + (size_t)4 * 1024 * 1024);
    unsigned short* v_t   = (unsigned short*)(ws + (size_t)8 * 1024 * 1024);
    float*          att_ws = (float*)(ws + (size_t)12 * 1024 * 1024);

    qkv_proj_kernel<<<dim3(TOKENS / 64, 6), 256, 0, stream>>>(x, Wqkv, q_bf, k_bf, v_t);
    attn_mfma_kernel<<<1024, 256, 0, stream>>>(q_bf, k_bf, v_t, att_ws);
    out_proj_kernel<<<dim3(TOKENS / 64, 2), 256, 0, stream>>>(att_ws, Wout, out);
}

// Round 13
// 125.658 us; speedup vs baseline: 1.0941x; 1.0266x over previous
//
#include <hip/hip_runtime.h>
#include <math.h>

// Problem constants (reference: B=4, T=4096, D_MODEL=128, N_HEADS=4, HEAD_DIM=32)
#define B_   4
#define T_   4096
#define DM_  128
#define NH_  4
#define HD_  32
#define TOKENS (B_ * T_)               // 16384

typedef __attribute__((ext_vector_type(8))) short short8;   // 8 bf16 = 4 VGPRs (MFMA A/B frag)
typedef __attribute__((ext_vector_type(4))) float floatx4;  // MFMA C/D frag

__device__ __forceinline__ unsigned short f2bf(float f) {
    union { float f; unsigned int u; } v; v.f = f;
    unsigned int u = v.u;
    u += 0x7fffu + ((u >> 16) & 1u);   // round-to-nearest-even
    return (unsigned short)(u >> 16);
}
__device__ __forceinline__ void split_bf(float v, unsigned short& hi, unsigned short& lo) {
    unsigned short h = f2bf(v);
    float hf = __uint_as_float(((unsigned int)h) << 16);
    hi = h;
    lo = f2bf(v - hf);
}

// LDS row stride for bf16 W tiles: 128 elements + 8 pad = 136 shorts = 272 B.
#define LROW 136

// -------------------------------------------------------------------------
// Kernel 1: QKV projection via MFMA, hi/lo bf16 split, coalesced epilogue.
// (round-6/9 version, unchanged)
// -------------------------------------------------------------------------
__global__ __launch_bounds__(256) void qkv_proj_kernel(
    const float* __restrict__ x, const float* __restrict__ Wqkv,
    unsigned short* __restrict__ q_bf, unsigned short* __restrict__ k_bf,
    unsigned short* __restrict__ v_t)
{
    __shared__ __align__(16) unsigned short whi[64 * LROW];   // 17 KB
    __shared__ __align__(16) unsigned short wlo[64 * LROW];   // 17 KB

    const int tid  = threadIdx.x;
    const int wave = tid >> 6, lane = tid & 63;
    const int m    = lane & 15, q4 = lane >> 4;
    const int m0   = blockIdx.x * 64;
    const int ch   = blockIdx.y;                  // 0..5
    const float scale = 0.2550052509571414f;      // log2(e)/sqrt(32)

    {   // cooperative W chunk split: rows ch*64 .. +63
        const float4* wg = (const float4*)(Wqkv + (size_t)ch * 64 * DM_);
        #pragma unroll
        for (int i = 0; i < 8; ++i) {
            const int f = tid + 256 * i;
            float4 v = wg[f];
            const int row = f >> 5, k4 = f & 31;
            ushort4 h, l;
            split_bf(v.x, h.x, l.x); split_bf(v.y, h.y, l.y);
            split_bf(v.z, h.z, l.z); split_bf(v.w, h.w, l.w);
            *(ushort4*)(whi + row * LROW + k4 * 4) = h;
            *(ushort4*)(wlo + row * LROW + k4 * 4) = l;
        }
    }

    // A-frags direct from global: row m0+wave*16+m, cols ks*32+q4*8..+7
    short8 Ah[4], Al[4];
    {
        const float4* xg = (const float4*)(x + (size_t)(m0 + wave * 16 + m) * DM_);
        #pragma unroll
        for (int ks = 0; ks < 4; ++ks) {
            float4 a = xg[ks * 8 + q4 * 2];
            float4 b = xg[ks * 8 + q4 * 2 + 1];
            ushort4 h0, l0, h1, l1;
            split_bf(a.x, h0.x, l0.x); split_bf(a.y, h0.y, l0.y);
            split_bf(a.z, h0.z, l0.z); split_bf(a.w, h0.w, l0.w);
            split_bf(b.x, h1.x, l1.x); split_bf(b.y, h1.y, l1.y);
            split_bf(b.z, h1.z, l1.z); split_bf(b.w, h1.w, l1.w);
            Ah[ks] = short8{(short)h0.x, (short)h0.y, (short)h0.z, (short)h0.w,
                            (short)h1.x, (short)h1.y, (short)h1.z, (short)h1.w};
            Al[ks] = short8{(short)l0.x, (short)l0.y, (short)l0.z, (short)l0.w,
                            (short)l1.x, (short)l1.y, (short)l1.z, (short)l1.w};
        }
    }
    __syncthreads();

    floatx4 acc[4];
    #pragma unroll
    for (int nb = 0; nb < 4; ++nb) {
        floatx4 a = {0.f, 0.f, 0.f, 0.f};
        #pragma unroll
        for (int ks = 0; ks < 4; ++ks) {
            short8 Bh = *(const short8*)(whi + (nb * 16 + m) * LROW + ks * 32 + q4 * 8);
            short8 Bl = *(const short8*)(wlo + (nb * 16 + m) * LROW + ks * 32 + q4 * 8);
            a = __builtin_amdgcn_mfma_f32_16x16x32_bf16(Ah[ks], Bh, a, 0, 0, 0);
            a = __builtin_amdgcn_mfma_f32_16x16x32_bf16(Ah[ks], Bl, a, 0, 0, 0);
            a = __builtin_amdgcn_mfma_f32_16x16x32_bf16(Al[ks], Bh, a, 0, 0, 0);
        }
        acc[nb] = a;
    }
    __syncthreads();   // all waves done reading whi/wlo -> reuse whi as staging

    // stage C tile as bf16: [64 t][72] for q/k (t-major), [64 n][72] for v (n-major)
    unsigned short* stage = whi;
    const bool isV = (ch >= 4);
    if (isV) {
        #pragma unroll
        for (int nb = 0; nb < 4; ++nb) {
            ushort4 p;
            p.x = f2bf(acc[nb][0]); p.y = f2bf(acc[nb][1]);
            p.z = f2bf(acc[nb][2]); p.w = f2bf(acc[nb][3]);
            *(ushort4*)(stage + (nb * 16 + m) * 72 + wave * 16 + q4 * 4) = p;
        }
    } else {
        const float scl = (ch < 2) ? scale : 1.0f;
        #pragma unroll
        for (int nb = 0; nb < 4; ++nb)
            #pragma unroll
            for (int reg = 0; reg < 4; ++reg)
                stage[(wave * 16 + q4 * 4 + reg) * 72 + nb * 16 + m]
                    = f2bf(acc[nb][reg] * scl);
    }
    __syncthreads();

    // coalesced write-out: 32B (2 x short8) per thread
    const int b    = m0 >> 12;
    const int t0   = m0 & (T_ - 1);
    const int head = tid >> 7;                 // 0..1 (n_local 0..31 / 32..63)
    const int hh   = (ch * 2 + head) & 3;
    const int bh   = b * NH_ + hh;
    const int r    = tid & 127;
    if (isV) {
        const int d = r >> 2, qc = r & 3;      // 32 d-rows x 4 t-chunks of 16
        const unsigned short* sp = stage + (head * 32 + d) * 72 + qc * 16;
        short8 v0 = *(const short8*)(sp);
        short8 v1 = *(const short8*)(sp + 8);
        unsigned short* gp = v_t + ((size_t)bh * HD_ + d) * T_ + t0 + qc * 16;
        *(short8*)(gp)     = v0;
        *(short8*)(gp + 8) = v1;
    } else {
        unsigned short* dst = (ch < 2) ? q_bf : k_bf;
        const int t = r >> 1, half = r & 1;    // 64 t-rows x 2 x 32B halves
        const unsigned short* sp = stage + t * 72 + head * 32 + half * 16;
        short8 v0 = *(const short8*)(sp);
        short8 v1 = *(const short8*)(sp + 8);
        unsigned short* gp = dst + ((size_t)bh * T_ + t0 + t) * HD_ + half * 16;
        *(short8*)(gp)     = v0;
        *(short8*)(gp + 8) = v1;
    }
}

// -------------------------------------------------------------------------
// Kernel 2: bf16 MFMA causal flash attention — round-12 structure (32 KB
// swizzled LDS, async-STAGE, ones-MFMA psum) with three VALU cuts:
//  (1) all swizzled LDS offsets hoisted to loop-invariant registers,
//      const-indexed in the unrolled tile (no per-step XOR/shift math);
//  (2) truncating P pack (no +0x8000): ls is summed by ones-MFMA from the
//      SAME packed bf16 P that PV consumes, so O = sum(P̂V)/sum(P̂) stays
//      self-consistent; only P quantization mode changes;
//  (3) exact alpha-skip: when __all(rmax <= mx), alpha == exp2(0) == 1
//      exactly -> skip exp2, 8 O-mults, ls-mult (bit-identical result).
// -------------------------------------------------------------------------
template<bool LAST>
__device__ __forceinline__ void attn_tile128(
    const char* kLds, const char* vLds, char* pT,
    const int* kOff, const int* pWr, const int* pRd,
    const int* vOffA, const int* vOffB,
    const int m, const int q4, const short8 qf, const short8 ones,
    const int sbN_in, const int limit,
    floatx4& O0, floatx4& O1, float& mx, float& ls)
{
    const int sbN = LAST ? sbN_in : 8;        // active 16-key sub-frags
    const int kN  = sbN >> 1;                 // active 32-key PV slots

    // S^T = K·Q^T : A = K rows (s), B = Q rows (q).  C[s=q4*4+reg][q=m]
    floatx4 st[8];
    #pragma unroll
    for (int sb = 0; sb < 8; ++sb) {
        if (sb >= sbN) continue;
        short8 kfrag = *(const short8*)(kLds + kOff[sb]);
        floatx4 z = {0.f, 0.f, 0.f, 0.f};
        st[sb] = __builtin_amdgcn_mfma_f32_16x16x32_bf16(kfrag, qf, z, 0, 0, 0);
    }

    if (LAST) {   // causal: mask s_local > limit
        #pragma unroll
        for (int sb = 0; sb < 8; ++sb) {
            if (sb >= sbN) continue;
            #pragma unroll
            for (int reg = 0; reg < 4; ++reg)
                if (sb * 16 + q4 * 4 + reg > limit) st[sb][reg] = -INFINITY;
        }
    }

    // per-lane row max over 32 s-values (tree) + 2 cross-quad shuffles
    float fm[8];
    #pragma unroll
    for (int sb = 0; sb < 8; ++sb)
        fm[sb] = (sb < sbN) ? fmaxf(fmaxf(st[sb][0], st[sb][1]),
                                    fmaxf(st[sb][2], st[sb][3]))
                            : -INFINITY;
    float rmax = fmaxf(fmaxf(fmaxf(fm[0], fm[1]), fmaxf(fm[2], fm[3])),
                       fmaxf(fmaxf(fm[4], fm[5]), fmaxf(fm[6], fm[7])));
    rmax = fmaxf(rmax, __shfl_xor(rmax, 16, 64));
    rmax = fmaxf(rmax, __shfl_xor(rmax, 32, 64));

    // exact alpha-skip: rmax <= mx on all lanes -> alpha == 1 exactly
    const bool upd = !__all(rmax <= mx);
    if (upd) {
        const float mn = fmaxf(mx, rmax);
        const float alpha = __builtin_amdgcn_exp2f(mx - mn);   // exp2(-inf)=0 first step
        mx = mn;
        #pragma unroll
        for (int reg = 0; reg < 4; ++reg) { O0[reg] *= alpha; O1[reg] *= alpha; }
        ls *= alpha;
    }

    // p = exp2(s - mx); truncating bf16 pack via v_perm (hi16 of each f32)
    // swizzled 16B granule: g = (2*sb + (q4>>1)) ^ m, half = q4&1
    #pragma unroll
    for (int sb = 0; sb < 8; ++sb) {
        if (sb >= sbN) continue;
        float p0 = __builtin_amdgcn_exp2f(st[sb][0] - mx);
        float p1 = __builtin_amdgcn_exp2f(st[sb][1] - mx);
        float p2 = __builtin_amdgcn_exp2f(st[sb][2] - mx);
        float p3 = __builtin_amdgcn_exp2f(st[sb][3] - mx);
        uint2 pk;
        pk.x = __builtin_amdgcn_perm(__float_as_uint(p1), __float_as_uint(p0),
                                     0x07060302);   // [bf(p0) | bf(p1)<<16]
        pk.y = __builtin_amdgcn_perm(__float_as_uint(p3), __float_as_uint(p2),
                                     0x07060302);
        *(uint2*)(pT + pWr[sb]) = pk;
    }

    // drain wave-internal P^T writes before cross-lane B-frag reads
    __asm__ volatile("s_waitcnt lgkmcnt(0)" ::: "memory");
    __builtin_amdgcn_sched_barrier(0);   // rule #18: keep MFMA below the fence

    // O^T += V^T · P^T ; row-sum of P via ones-MFMA (C row = col-sum of B):
    // ps[reg] = sum_k P^T[k][q=m], identical across regs -> no shuffles.
    floatx4 ps = {0.f, 0.f, 0.f, 0.f};
    #pragma unroll
    for (int ks = 0; ks < 4; ++ks) {
        if (ks >= kN) continue;
        short8 bfrag = *(const short8*)(pT + pRd[ks]);
        short8 va = *(const short8*)(vLds + vOffA[ks]);
        short8 vb = *(const short8*)(vLds + vOffB[ks]);
        O0 = __builtin_amdgcn_mfma_f32_16x16x32_bf16(va, bfrag, O0, 0, 0, 0);
        O1 = __builtin_amdgcn_mfma_f32_16x16x32_bf16(vb, bfrag, O1, 0, 0, 0);
        ps = __builtin_amdgcn_mfma_f32_16x16x32_bf16(ones, bfrag, ps, 0, 0, 0);
    }
    ls += ps[0];
}

__global__ __launch_bounds__(256, 4) void attn_mfma_kernel(
    const unsigned short* __restrict__ qb, const unsigned short* __restrict__ kb,
    const unsigned short* __restrict__ vtb, float* __restrict__ og)
{
    // LDS (swizzled, no padding): K 8192 | V^T 8192 | P^T 4x4096 = 32768 B
    __shared__ __align__(16) char smem[32768];
    char* kLds = smem;
    char* vLds = smem + 8192;
    const int tid  = threadIdx.x;
    const int wave = tid >> 6, lane = tid & 63;
    const int m    = lane & 15, q4 = lane >> 4;
    char* pT = smem + 16384 + wave * 4096 + m * 256;   // this lane's P^T row base

    // Dispatch swizzle: XCD-locality (2 heads per XCD) + per-CU qt balance.
    const int pid = blockIdx.x;
    const int xcd = pid & 7;
    const int r_  = pid >> 3;
    const int bh  = xcd * 2 + (r_ & 1);
    const int j_  = r_ >> 1;
    const int a_  = j_ & 15, k_ = j_ >> 4;
    const int qt  = (k_ == 0) ? a_ : (k_ == 1) ? 63 - a_
                  : (k_ == 2) ? 32 + a_ : 31 - a_;

    const size_t qkbase = (size_t)bh * T_ * HD_;
    const char* kg = (const char*)(kb + qkbase);
    const char* vg = (const char*)(vtb + qkbase);

    // Q B-fragment: row qt*64+wave*16+m, k-bytes q4*16 (Q pre-scaled, exp2 domain)
    short8 qf = *(const short8*)((const char*)(qb + qkbase)
                 + (size_t)(qt * 64 + wave * 16 + m) * 64 + q4 * 16);
    const int qrow = wave * 16 + m;        // query row within the 64-block

    const short8 ones = short8{(short)0x3F80, (short)0x3F80, (short)0x3F80,
                               (short)0x3F80, (short)0x3F80, (short)0x3F80,
                               (short)0x3F80, (short)0x3F80};   // bf16 1.0 x8

    // hoisted loop-invariant swizzled offsets (const-indexed after unroll)
    int kOff[8], pWr[8], pRd[4], vOffA[4], vOffB[4];
    #pragma unroll
    for (int sb = 0; sb < 8; ++sb) {
        kOff[sb] = (sb * 16 + m) * 64 + ((q4 ^ (m & 3)) << 4);
        pWr[sb]  = ((((2 * sb + (q4 >> 1)) ^ m) << 4) + (q4 & 1) * 8);
    }
    #pragma unroll
    for (int ks = 0; ks < 4; ++ks) {
        const int g = ((ks * 4 + q4) ^ m) << 4;
        pRd[ks]   = g;
        vOffA[ks] = m * 256 + g;
        vOffB[ks] = (16 + m) * 256 + g;
    }

    floatx4 O0 = {0.f, 0.f, 0.f, 0.f}, O1 = {0.f, 0.f, 0.f, 0.f};
    float mx = -INFINITY, ls = 0.f;

    const int itN      = (qt >> 1) + 1;            // 128-key steps
    const int sbN_last = (qt & 1) ? 8 : 4;         // active sub-frags on diagonal
    const int limit    = ((qt & 1) << 6) + qrow;   // causal mask threshold

    // async-STAGE: per-thread staging addresses + prologue load of step 0
    const int krow = tid >> 2, ku = tid & 3;
    const int vd = tid >> 3, vu = tid & 7;
    const char* kstage = kg + (size_t)krow * 64 + ku * 16;
    const char* vstage = vg + (size_t)vd * (T_ * 2) + vu * 16;

    // swizzled LDS destinations (constant per thread)
    const int kdst = krow * 64 + ((ku ^ (krow & 3)) << 4);
    const int vdst = vd * 256 + ((vu ^ (vd & 15)) << 4);

    short8 sk0 = *(const short8*)(kstage);
    short8 sk1 = *(const short8*)(kstage + 64 * 64);
    short8 sv0 = *(const short8*)(vstage);
    short8 sv1 = *(const short8*)(vstage + 128);

    for (int it = 0; it < itN; ++it) {
        __syncthreads();   // all waves done reading LDS of previous step
        *(short8*)(kLds + kdst) = sk0;
        *(short8*)(kLds + 64 * 64 + kdst) = sk1;       // row 64+krow: same xor key
        *(short8*)(vLds + vdst) = sv0;
        *(short8*)(vLds + (vdst ^ 128)) = sv1;         // granule vu+8 = g^8
        __syncthreads();

        if (it + 1 < itN) {   // issue next step's loads; land during compute
            const size_t nb = (size_t)(it + 1) << 7;
            sk0 = *(const short8*)(kstage + nb * 64);
            sk1 = *(const short8*)(kstage + nb * 64 + 64 * 64);
            sv0 = *(const short8*)(vstage + nb * 2);
            sv1 = *(const short8*)(vstage + nb * 2 + 128);
            attn_tile128<false>(kLds, vLds, pT, kOff, pWr, pRd, vOffA, vOffB,
                                m, q4, qf, ones, 8, 0, O0, O1, mx, ls);
        } else {
            attn_tile128<true>(kLds, vLds, pT, kOff, pWr, pRd, vOffA, vOffB,
                               m, q4, qf, ones, sbN_last, limit,
                               O0, O1, mx, ls);
        }
    }

    // epilogue: O^T[d][q=m] -> lane holds d = q4*4+reg (+16);  t = per-lane row
    const float inv = 1.f / ls;
    const int b = bh >> 2, h = bh & 3;
    const int t = qt * 64 + qrow;
    float* orow = og + (((size_t)b * T_ + t) * NH_ + h) * HD_;
    *(float4*)(orow + q4 * 4)      = make_float4(O0[0] * inv, O0[1] * inv,
                                                 O0[2] * inv, O0[3] * inv);
    *(float4*)(orow + 16 + q4 * 4) = make_float4(O1[0] * inv, O1[1] * inv,
                                                 O1[2] * inv, O1[3] * inv);
}

// -------------------------------------------------------------------------
// Kernel 3: output projection via MFMA, hi/lo bf16 split.  (round-9 version)
// -------------------------------------------------------------------------
__global__ __launch_bounds__(256) void out_proj_kernel(
    const float* __restrict__ a, const float* __restrict__ Wout,
    float* __restrict__ out)
{
    __shared__ __align__(16) unsigned short whi[64 * LROW];
    __shared__ __align__(16) unsigned short wlo[64 * LROW];

    const int tid  = threadIdx.x;
    const int wave = tid >> 6, lane = tid & 63;
    const int m    = lane & 15, q4 = lane >> 4;
    const int m0   = blockIdx.x * 64;
    const int ch   = blockIdx.y;                  // 0..1

    {   // cooperative W chunk split
        const float4* wg = (const float4*)(Wout + (size_t)ch * 64 * DM_);
        #pragma unroll
        for (int i = 0; i < 8; ++i) {
            const int f = tid + 256 * i;
            float4 v = wg[f];
            const int row = f >> 5, k4 = f & 31;
            ushort4 h, l;
            split_bf(v.x, h.x, l.x); split_bf(v.y, h.y, l.y);
            split_bf(v.z, h.z, l.z); split_bf(v.w, h.w, l.w);
            *(ushort4*)(whi + row * LROW + k4 * 4) = h;
            *(ushort4*)(wlo + row * LROW + k4 * 4) = l;
        }
    }

    short8 Ah[4], Al[4];
    {
        const float4* xg = (const float4*)(a + (size_t)(m0 + wave * 16 + m) * DM_);
        #pragma unroll
        for (int ks = 0; ks < 4; ++ks) {
            float4 av = xg[ks * 8 + q4 * 2];
            float4 bv = xg[ks * 8 + q4 * 2 + 1];
            ushort4 h0, l0, h1, l1;
            split_bf(av.x, h0.x, l0.x); split_bf(av.y, h0.y, l0.y);
            split_bf(av.z, h0.z, l0.z); split_bf(av.w, h0.w, l0.w);
            split_bf(bv.x, h1.x, l1.x); split_bf(bv.y, h1.y, l1.y);
            split_bf(bv.z, h1.z, l1.z); split_bf(bv.w, h1.w, l1.w);
            Ah[ks] = short8{(short)h0.x, (short)h0.y, (short)h0.z, (short)h0.w,
                            (short)h1.x, (short)h1.y, (short)h1.z, (short)h1.w};
            Al[ks] = short8{(short)l0.x, (short)l0.y, (short)l0.z, (short)l0.w,
                            (short)l1.x, (short)l1.y, (short)l1.z, (short)l1.w};
        }
    }
    __syncthreads();

    #pragma unroll
    for (int nb = 0; nb < 4; ++nb) {
        floatx4 acc = {0.f, 0.f, 0.f, 0.f};
        #pragma unroll
        for (int ks = 0; ks < 4; ++ks) {
            short8 Bh = *(const short8*)(whi + (nb * 16 + m) * LROW + ks * 32 + q4 * 8);
            short8 Bl = *(const short8*)(wlo + (nb * 16 + m) * LROW + ks * 32 + q4 * 8);
            acc = __builtin_amdgcn_mfma_f32_16x16x32_bf16(Ah[ks], Bh, acc, 0, 0, 0);
            acc = __builtin_amdgcn_mfma_f32_16x16x32_bf16(Ah[ks], Bl, acc, 0, 0, 0);
            acc = __builtin_amdgcn_mfma_f32_16x16x32_bf16(Al[ks], Bh, acc, 0, 0, 0);
        }
        const int n = ch * 64 + nb * 16 + m;
        const int tok0 = m0 + wave * 16 + q4 * 4;
        #pragma unroll
        for (int reg = 0; reg < 4; ++reg)
            out[(size_t)(tok0 + reg) * DM_ + n] = acc[reg];
    }
}

// -------------------------------------------------------------------------
extern "C" void kernel_launch(void* const* d_in, const int* in_sizes, int n_in,
                              void* d_out, int out_size, void* d_ws, size_t ws_size,
                              hipStream_t stream) {
    const float* x    = (const float*)d_in[0];   // (4,4096,128) fp32
    const float* Wqkv = (const float*)d_in[1];   // (384,128)    fp32
    const float* Wout = (const float*)d_in[2];   // (128,128)    fp32
    float* out = (float*)d_out;                  // (4,4096,128) fp32

    // ws layout (bytes): q_bf 4MB | k_bf 4MB | v_t 4MB | att_ws fp32 8MB
    char* ws = (char*)d_ws;
    unsigned short* q_bf  = (unsigned short*)(ws);
    unsigned short* k_bf  = (unsigned short*)(ws + (size_t)4 * 1024 * 1024);
    unsigned short* v_t   = (unsigned short*)(ws + (size_t)8 * 1024 * 1024);
    float*          att_ws = (float*)(ws + (size_t)12 * 1024 * 1024);

    qkv_proj_kernel<<<dim3(TOKENS / 64, 6), 256, 0, stream>>>(x, Wqkv, q_bf, k_bf, v_t);
    attn_mfma_kernel<<<1024, 256, 0, stream>>>(q_bf, k_bf, v_t, att_ws);
    out_proj_kernel<<<dim3(TOKENS / 64, 2), 256, 0, stream>>>(att_ws, Wout, out);
}